// Round 5
// baseline (477.752 us; speedup 1.0000x reference)
//
#include <hip/hip_runtime.h>
#include <hip/hip_bf16.h>

typedef __bf16 bf16_t;
typedef __bf16 bf16x8 __attribute__((ext_vector_type(8)));
typedef __bf16 bf16x4 __attribute__((ext_vector_type(4)));
typedef float f32x4 __attribute__((ext_vector_type(4)));
typedef unsigned int u32;
typedef const __attribute__((address_space(1))) u32* gptr_t;
typedef __attribute__((address_space(3))) u32* lptr_t;

static constexpr int Bb = 16, Ss = 1024, Hh = 768;
static constexpr int MTOK = Bb * Ss; // 16384

// ---- merged conversion: x -> bf16, 5 weights -> bf16 slab, pack bqkv ----
__global__ __launch_bounds__(256) void cvt_all(
    const float* __restrict__ x,
    const float* __restrict__ w0, const float* __restrict__ w1,
    const float* __restrict__ w2, const float* __restrict__ w3,
    const float* __restrict__ w4,
    const float* __restrict__ bq, const float* __restrict__ bk,
    const float* __restrict__ bv,
    bf16_t* __restrict__ xb, bf16_t* __restrict__ wdst, float* __restrict__ bdst)
{
    int bx = blockIdx.x;
    if (bx < 12288) {
        int i = bx * 256 + threadIdx.x;
        float4 v = ((const float4*)x)[i];
        bf16x4 o = { (bf16_t)v.x, (bf16_t)v.y, (bf16_t)v.z, (bf16_t)v.w };
        ((bf16x4*)xb)[i] = o;
    } else if (bx < 15168) {
        int b2 = bx - 12288;
        int seg = b2 / 576;
        const float* src = seg == 0 ? w0 : seg == 1 ? w1 : seg == 2 ? w2 : seg == 3 ? w3 : w4;
        int i = (b2 % 576) * 256 + threadIdx.x;
        float4 v = ((const float4*)src)[i];
        bf16x4 o = { (bf16_t)v.x, (bf16_t)v.y, (bf16_t)v.z, (bf16_t)v.w };
        ((bf16x4*)(wdst + (long)seg * 589824))[i] = o;
    } else {
        int i = (bx - 15168) * 256 + threadIdx.x;
        if (i < 2304)
            bdst[i] = i < 768 ? bq[i] : i < 1536 ? bk[i - 768] : bv[i - 1536];
    }
}

// ---------------- async global->LDS 16B ----------------
__device__ __forceinline__ void async_cp16(const void* g, void* l)
{
    __builtin_amdgcn_global_load_lds((gptr_t)g, (lptr_t)l, 16, 0, 0);
}

enum { EG_RELU_BIAS_B16 = 0, EG_QKV = 1, EG_SCORE_T = 2, EG_B16 = 3, EG_FINAL = 4 };

// C = epi(A * B^T); A:[M,K] k-contig, B:[N,K] k-contig, bf16 in, fp32 accum.
// 128x128 tile, BK=32, 4 waves (2x2), mfma_f32_16x16x32_bf16 4x4 per wave.
// LDS identity/k-major layout: 16-row group g occupies a 1KB block; within it
// byte offset = lane*16 where lane = kchunk*16 + row. Staging DMA writes it in
// exactly that order, fragment ds_read_b128 is conflict-free (R4-measured: 0),
// and 4x4 accumulators give 16 indep MFMA chains (R4's 2x2 latency-stalled).
template <int EPI>
__global__ __launch_bounds__(256) void mfma_gemm(
    const bf16_t* __restrict__ A, const bf16_t* __restrict__ B,
    const float* __restrict__ bias, const bf16_t* __restrict__ resid,
    const int* __restrict__ mask, void* __restrict__ Cout,
    bf16_t* __restrict__ out2, bf16_t* __restrict__ out3,
    int K, int lda, int ldb, int ldc,
    long sA, long sB, long sC, float scale)
{
    __shared__ bf16_t Asl[128 * 32];
    __shared__ bf16_t Bsl[128 * 32];

    const int tid = threadIdx.x;
    const int wid = tid >> 6;
    const int lane = tid & 63;
    const int wm = wid & 1, wn = wid >> 1;
    const int m0 = blockIdx.y * 128;
    const int n0 = blockIdx.x * 128;
    const int bz = blockIdx.z;

    const bf16_t* Ab = A + (long)bz * sA;
    const bf16_t* Bp = B + (long)bz * sB;

    // staging: lane l of wave w loads 16B from row w*16+(l&15), kcol (l>>4)*8
    const int srow = (wid << 4) + (lane & 15);
    const int scol = (lane >> 4) << 3;

    const bf16_t* pa0 = Ab + (long)(m0 + srow) * lda + scol;
    const bf16_t* pa1 = Ab + (long)(m0 + 64 + srow) * lda + scol;
    const bf16_t* pb0 = Bp + (long)(n0 + srow) * ldb + scol;
    const bf16_t* pb1 = Bp + (long)(n0 + 64 + srow) * ldb + scol;

    bf16_t* la = &Asl[wid << 9];   // wave-uniform LDS bases (group block = wid)
    bf16_t* lb = &Bsl[wid << 9];

    const int lane8 = lane << 3;   // fragment read: lane*16B within group block

    f32x4 acc[4][4] = {};

    for (int k0 = 0; k0 < K; k0 += 32) {
        async_cp16(pa0 + k0, la);
        async_cp16(pa1 + k0, la + 2048);
        async_cp16(pb0 + k0, lb);
        async_cp16(pb1 + k0, lb + 2048);
        __syncthreads();

        bf16x8 af[4], bfr[4];
#pragma unroll
        for (int i = 0; i < 4; i++)
            af[i] = *(const bf16x8*)&Asl[(((wm << 2) + i) << 9) + lane8];
#pragma unroll
        for (int j = 0; j < 4; j++)
            bfr[j] = *(const bf16x8*)&Bsl[(((wn << 2) + j) << 9) + lane8];
#pragma unroll
        for (int i = 0; i < 4; i++)
#pragma unroll
            for (int j = 0; j < 4; j++)
                acc[i][j] = __builtin_amdgcn_mfma_f32_16x16x32_bf16(af[i], bfr[j], acc[i][j], 0, 0, 0);
        __syncthreads();
    }

    // epilogue — C/D layout per 16x16 tile: col = lane&15, row = (lane>>4)*4 + reg
    const int mb_ = m0 + (wm << 6);
    const int nb_ = n0 + (wn << 6);
    const int colw = lane & 15;
    const int rowq = (lane >> 4) << 2;

    if constexpr (EPI == EG_QKV) {
        // cols 0..767 -> q (relu+bias), 768..1535 -> k (relu+bias), 1536..2303 -> vT
        float bj[4];
#pragma unroll
        for (int j = 0; j < 4; j++) bj[j] = bias[nb_ + (j << 4) + colw];
        if (nb_ < 1536) {
            bf16_t* C = (nb_ < 768) ? (bf16_t*)Cout : out2;
            const int cb = (nb_ < 768) ? nb_ : nb_ - 768;
#pragma unroll
            for (int i = 0; i < 4; i++)
#pragma unroll
                for (int j = 0; j < 4; j++)
#pragma unroll
                    for (int r = 0; r < 4; r++) {
                        int row = mb_ + (i << 4) + rowq + r;
                        int col = cb + (j << 4) + colw;
                        float v = fmaxf(acc[i][j][r] + bj[j], 0.f);
                        C[(long)row * Hh + col] = (bf16_t)v;
                    }
        } else {
#pragma unroll
            for (int i = 0; i < 4; i++) {
                const int sAbs = mb_ + (i << 4) + rowq;
                const int b = sAbs >> 10;
                const int sl = sAbs & 1023;
#pragma unroll
                for (int j = 0; j < 4; j++) {
                    const int col = nb_ - 1536 + (j << 4) + colw;
                    bf16x4 o = { (bf16_t)(acc[i][j][0] + bj[j]), (bf16_t)(acc[i][j][1] + bj[j]),
                                 (bf16_t)(acc[i][j][2] + bj[j]), (bf16_t)(acc[i][j][3] + bj[j]) };
                    *(bf16x4*)&out3[((long)b * Hh + col) * Ss + sl] = o;
                }
            }
        }
    } else if constexpr (EPI == EG_SCORE_T) {
        // computed T = k·q^T; rows = keys, cols = queries; store S = T^T (bf16)
        bf16_t* C = (bf16_t*)Cout + (long)bz * sC;
        const int* mk = mask + bz * Ss;
        int mq[4];
#pragma unroll
        for (int j = 0; j < 4; j++) mq[j] = mk[nb_ + (j << 4) + colw];
#pragma unroll
        for (int i = 0; i < 4; i++) {
            const int kbase = mb_ + (i << 4) + rowq;
            int4 mkey = *(const int4*)&mk[kbase];
#pragma unroll
            for (int j = 0; j < 4; j++) {
                const int qrow = nb_ + (j << 4) + colw;
                bf16x4 o;
                o[0] = (mkey.x & mq[j]) ? (bf16_t)(acc[i][j][0] * scale) : (bf16_t)(-1e12f);
                o[1] = (mkey.y & mq[j]) ? (bf16_t)(acc[i][j][1] * scale) : (bf16_t)(-1e12f);
                o[2] = (mkey.z & mq[j]) ? (bf16_t)(acc[i][j][2] * scale) : (bf16_t)(-1e12f);
                o[3] = (mkey.w & mq[j]) ? (bf16_t)(acc[i][j][3] * scale) : (bf16_t)(-1e12f);
                *(bf16x4*)&C[(long)qrow * ldc + kbase] = o;
            }
        }
    } else if constexpr (EPI == EG_FINAL) {
        float* C = (float*)Cout;
        float bj[4];
#pragma unroll
        for (int j = 0; j < 4; j++) bj[j] = bias[nb_ + (j << 4) + colw];
#pragma unroll
        for (int i = 0; i < 4; i++)
#pragma unroll
            for (int j = 0; j < 4; j++)
#pragma unroll
                for (int r = 0; r < 4; r++) {
                    int row = mb_ + (i << 4) + rowq + r;
                    int col = nb_ + (j << 4) + colw;
                    C[(long)row * ldc + col] =
                        acc[i][j][r] + bj[j] + (float)resid[(long)row * ldc + col];
                }
    } else {
        // EG_RELU_BIAS_B16 / EG_B16 -> bf16 output
        bf16_t* C = (bf16_t*)Cout + (long)bz * sC;
        float bj[4] = {0.f, 0.f, 0.f, 0.f};
        if constexpr (EPI == EG_RELU_BIAS_B16) {
#pragma unroll
            for (int j = 0; j < 4; j++) bj[j] = bias[nb_ + (j << 4) + colw];
        }
#pragma unroll
        for (int i = 0; i < 4; i++)
#pragma unroll
            for (int j = 0; j < 4; j++)
#pragma unroll
                for (int r = 0; r < 4; r++) {
                    int row = mb_ + (i << 4) + rowq + r;
                    int col = nb_ + (j << 4) + colw;
                    float v = acc[i][j][r] + bj[j];
                    if constexpr (EPI == EG_RELU_BIAS_B16) v = fmaxf(v, 0.f);
                    C[(long)row * ldc + col] = (bf16_t)v;
                }
    }
}

// ---------------- masked softmax, bf16 in / bf16 out (in place) ----------------
__global__ __launch_bounds__(256) void softmax_rows(bf16_t* __restrict__ S_,
                                                    const int* __restrict__ mask)
{
    const int row = blockIdx.x;
    const int b = row >> 10;
    const int s = row & 1023;
    bf16_t* p = S_ + (long)row * Ss;
    const int* mk = mask + b * Ss;
    const int t = threadIdx.x;
    const int t0 = t << 2;

    bf16x4 v4 = *(const bf16x4*)&p[t0];
    float v0 = (float)v4[0], v1 = (float)v4[1], v2 = (float)v4[2], v3 = (float)v4[3];

    float mx = fmaxf(fmaxf(v0, v1), fmaxf(v2, v3));
#pragma unroll
    for (int off = 32; off; off >>= 1) mx = fmaxf(mx, __shfl_down(mx, off, 64));
    __shared__ float redm[4], reds[4];
    if ((t & 63) == 0) redm[t >> 6] = mx;
    __syncthreads();
    mx = fmaxf(fmaxf(redm[0], redm[1]), fmaxf(redm[2], redm[3]));

    float e0 = __expf(v0 - mx), e1 = __expf(v1 - mx);
    float e2 = __expf(v2 - mx), e3 = __expf(v3 - mx);
    float sm = e0 + e1 + e2 + e3;
#pragma unroll
    for (int off = 32; off; off >>= 1) sm += __shfl_down(sm, off, 64);
    if ((t & 63) == 0) reds[t >> 6] = sm;
    __syncthreads();
    sm = reds[0] + reds[1] + reds[2] + reds[3];

    const float inv = 1.f / sm;
    const float fs = (float)mk[s];
    bf16x4 o = { (bf16_t)(e0 * inv * fs * (float)mk[t0 + 0]),
                 (bf16_t)(e1 * inv * fs * (float)mk[t0 + 1]),
                 (bf16_t)(e2 * inv * fs * (float)mk[t0 + 2]),
                 (bf16_t)(e3 * inv * fs * (float)mk[t0 + 3]) };
    *(bf16x4*)&p[t0] = o;
}

extern "C" void kernel_launch(void* const* d_in, const int* in_sizes, int n_in,
                              void* d_out, int out_size, void* d_ws, size_t ws_size,
                              hipStream_t stream)
{
    const float* x  = (const float*)d_in[0];
    const int* mask = (const int*)d_in[1];
    const float* Wq = (const float*)d_in[2];
    const float* bq = (const float*)d_in[3];
    const float* Wk = (const float*)d_in[4];
    const float* bk = (const float*)d_in[5];
    const float* Wv = (const float*)d_in[6];
    const float* bv = (const float*)d_in[7];
    const float* W1 = (const float*)d_in[8];
    const float* b1 = (const float*)d_in[9];
    const float* W2 = (const float*)d_in[10];
    const float* b2 = (const float*)d_in[11];
    float* out = (float*)d_out;

    // workspace layout (~140 MB)
    char* w = (char*)d_ws;
    bf16_t* xb   = (bf16_t*)(w + 0);            // [16384,768], reused as ctx
    bf16_t* qb   = (bf16_t*)(w + 25165824);     // reused as h1
    bf16_t* kb   = (bf16_t*)(w + 50331648);
    bf16_t* vT   = (bf16_t*)(w + 75497472);     // [16,768,1024]
    bf16_t* sc   = (bf16_t*)(w + 100663296);    // [16,1024,1024] bf16
    bf16_t* wqkv = (bf16_t*)(w + 134217728);    // [2304,768] = Wq|Wk|Wv
    bf16_t* w1b  = (bf16_t*)(w + 137756672);
    bf16_t* w2b  = (bf16_t*)(w + 138936320);
    float*  bqkv = (float*) (w + 140115968);    // [2304]
    bf16_t* ctx  = xb;
    bf16_t* h1   = qb;

    const float inv_sqrt_h = 0.036084391824351615f; // 1/sqrt(768)

    cvt_all<<<15177, 256, 0, stream>>>(x, Wq, Wk, Wv, W1, W2, bq, bk, bv, xb, wqkv, bqkv);

    dim3 blk(256);

    // fused q|k|vT = epi(x · [Wq|Wk|Wv]^T + bqkv)
    mfma_gemm<EG_QKV><<<dim3(18, 128, 1), blk, 0, stream>>>(
        xb, wqkv, bqkv, nullptr, nullptr, qb, kb, vT,
        768, 768, 768, 768, 0, 0, 0, 1.f);

    // sc[q][k] = (k·q^T)^T * scale with mask penalty, bf16
    mfma_gemm<EG_SCORE_T><<<dim3(8, 8, 16), blk, 0, stream>>>(
        kb, qb, nullptr, nullptr, mask, sc, nullptr, nullptr,
        768, 768, 768, 1024, 786432, 786432, 1048576, inv_sqrt_h);

    // masked softmax in place (bf16)
    softmax_rows<<<dim3(MTOK), blk, 0, stream>>>(sc, mask);

    // ctx = sc · vT^T
    mfma_gemm<EG_B16><<<dim3(6, 8, 16), blk, 0, stream>>>(
        sc, vT, nullptr, nullptr, nullptr, ctx, nullptr, nullptr,
        1024, 1024, 1024, 768, 1048576, 786432, 786432, 1.f);

    // h1 = relu(ctx · W1^T + b1)
    mfma_gemm<EG_RELU_BIAS_B16><<<dim3(6, 128, 1), blk, 0, stream>>>(
        ctx, w1b, b1, nullptr, nullptr, h1, nullptr, nullptr,
        768, 768, 768, 768, 0, 0, 0, 1.f);

    // out = h1 · W2^T + b2 + ctx  (fp32)
    mfma_gemm<EG_FINAL><<<dim3(6, 128, 1), blk, 0, stream>>>(
        h1, w2b, b2, ctx, nullptr, out, nullptr, nullptr,
        768, 768, 768, 768, 0, 0, 0, 1.f);
}

// Round 6
// 410.487 us; speedup vs baseline: 1.1639x; 1.1639x over previous
//
#include <hip/hip_runtime.h>
#include <hip/hip_bf16.h>

typedef __bf16 bf16_t;
typedef __bf16 bf16x8 __attribute__((ext_vector_type(8)));
typedef __bf16 bf16x4 __attribute__((ext_vector_type(4)));
typedef float f32x4 __attribute__((ext_vector_type(4)));
typedef unsigned int u32;
typedef const __attribute__((address_space(1))) u32* gptr_t;
typedef __attribute__((address_space(3))) u32* lptr_t;

static constexpr int Bb = 16, Ss = 1024, Hh = 768;
static constexpr int MTOK = Bb * Ss; // 16384

// ---- merged conversion: x -> bf16, 5 weights -> bf16 slab, pack bqkv ----
__global__ __launch_bounds__(256) void cvt_all(
    const float* __restrict__ x,
    const float* __restrict__ w0, const float* __restrict__ w1,
    const float* __restrict__ w2, const float* __restrict__ w3,
    const float* __restrict__ w4,
    const float* __restrict__ bq, const float* __restrict__ bk,
    const float* __restrict__ bv,
    bf16_t* __restrict__ xb, bf16_t* __restrict__ wdst, float* __restrict__ bdst)
{
    int bx = blockIdx.x;
    if (bx < 12288) {
        int i = bx * 256 + threadIdx.x;
        float4 v = ((const float4*)x)[i];
        bf16x4 o = { (bf16_t)v.x, (bf16_t)v.y, (bf16_t)v.z, (bf16_t)v.w };
        ((bf16x4*)xb)[i] = o;
    } else if (bx < 15168) {
        int b2 = bx - 12288;
        int seg = b2 / 576;
        const float* src = seg == 0 ? w0 : seg == 1 ? w1 : seg == 2 ? w2 : seg == 3 ? w3 : w4;
        int i = (b2 % 576) * 256 + threadIdx.x;
        float4 v = ((const float4*)src)[i];
        bf16x4 o = { (bf16_t)v.x, (bf16_t)v.y, (bf16_t)v.z, (bf16_t)v.w };
        ((bf16x4*)(wdst + (long)seg * 589824))[i] = o;
    } else {
        int i = (bx - 15168) * 256 + threadIdx.x;
        if (i < 2304)
            bdst[i] = i < 768 ? bq[i] : i < 1536 ? bk[i - 768] : bv[i - 1536];
    }
}

// ---------------- async global->LDS 16B ----------------
__device__ __forceinline__ void async_cp16(const void* g, void* l)
{
    __builtin_amdgcn_global_load_lds((gptr_t)g, (lptr_t)l, 16, 0, 0);
}

enum { EG_RELU_BIAS_B16 = 0, EG_QKV = 1, EG_SCORE_T = 2, EG_B16 = 3, EG_FINAL = 4 };

// C = epi(A * B^T); A:[M,K] k-contig, B:[N,K] k-contig, bf16 in, fp32 accum.
// 128x128 tile, BK=32, 4 waves (2x2), mfma_f32_16x16x32_bf16 4x4 per wave.
//
// XOR-swizzled LDS layout (fixes R3's 8-way conflicts AND R5's staging
// decoalescing): global_load_lds forces LDS dest = lane*16B, so the LDS
// layout IS the staging lane order. We pick lane l -> (row = l>>2,
// kchunk = (l&3) ^ ((l>>3)&3)): lane-quads cover one contiguous 64B global
// segment (coalesced like R3), and the fragment read
// offset = 32*(lane&15) + 8*((lane>>4) ^ ((lane>>1)&3)) spreads each
// 16-lane phase exactly 2 lanes/bank-group (2-way = free, m136).
template <int EPI>
__global__ __launch_bounds__(256) void mfma_gemm(
    const bf16_t* __restrict__ A, const bf16_t* __restrict__ B,
    const float* __restrict__ bias, const bf16_t* __restrict__ resid,
    const int* __restrict__ mask, void* __restrict__ Cout,
    bf16_t* __restrict__ out2, bf16_t* __restrict__ out3,
    int K, int lda, int ldb, int ldc,
    long sA, long sB, long sC, float scale)
{
    __shared__ bf16_t Asl[128 * 32];
    __shared__ bf16_t Bsl[128 * 32];

    const int tid = threadIdx.x;
    const int wid = tid >> 6;
    const int lane = tid & 63;
    const int wm = wid & 1, wn = wid >> 1;
    const int m0 = blockIdx.y * 128;
    const int n0 = blockIdx.x * 128;
    const int bz = blockIdx.z;

    const bf16_t* Ab = A + (long)bz * sA;
    const bf16_t* Bp = B + (long)bz * sB;

    // staging: lane l of wave w -> row w*16 + (l>>2), kchunk (l&3)^((l>>3)&3)
    const int srow = (wid << 4) + (lane >> 2);
    const int scol = ((lane & 3) ^ ((lane >> 3) & 3)) << 3;

    const bf16_t* pa0 = Ab + (long)(m0 + srow) * lda + scol;
    const bf16_t* pa1 = Ab + (long)(m0 + 64 + srow) * lda + scol;
    const bf16_t* pb0 = Bp + (long)(n0 + srow) * ldb + scol;
    const bf16_t* pb1 = Bp + (long)(n0 + 64 + srow) * ldb + scol;

    bf16_t* la = &Asl[wid << 9];   // wave-uniform LDS bases (group block = wid)
    bf16_t* lb = &Bsl[wid << 9];

    // fragment read offset within a 16-row group block (512 elems):
    // row = lane&15, kchunk = lane>>4, swizzled by g(row) = (row>>1)&3
    const int frag_off = ((lane & 15) << 5) + (((lane >> 4) ^ ((lane >> 1) & 3)) << 3);

    f32x4 acc[4][4] = {};

    for (int k0 = 0; k0 < K; k0 += 32) {
        async_cp16(pa0 + k0, la);
        async_cp16(pa1 + k0, la + 2048);
        async_cp16(pb0 + k0, lb);
        async_cp16(pb1 + k0, lb + 2048);
        __syncthreads();

        bf16x8 af[4], bfr[4];
#pragma unroll
        for (int i = 0; i < 4; i++)
            af[i] = *(const bf16x8*)&Asl[(((wm << 2) + i) << 9) + frag_off];
#pragma unroll
        for (int j = 0; j < 4; j++)
            bfr[j] = *(const bf16x8*)&Bsl[(((wn << 2) + j) << 9) + frag_off];
#pragma unroll
        for (int i = 0; i < 4; i++)
#pragma unroll
            for (int j = 0; j < 4; j++)
                acc[i][j] = __builtin_amdgcn_mfma_f32_16x16x32_bf16(af[i], bfr[j], acc[i][j], 0, 0, 0);
        __syncthreads();
    }

    // epilogue — C/D layout per 16x16 tile: col = lane&15, row = (lane>>4)*4 + reg
    const int mb_ = m0 + (wm << 6);
    const int nb_ = n0 + (wn << 6);
    const int colw = lane & 15;
    const int rowq = (lane >> 4) << 2;

    if constexpr (EPI == EG_QKV) {
        // cols 0..767 -> q (relu+bias), 768..1535 -> k (relu+bias), 1536..2303 -> vT
        float bj[4];
#pragma unroll
        for (int j = 0; j < 4; j++) bj[j] = bias[nb_ + (j << 4) + colw];
        if (nb_ < 1536) {
            bf16_t* C = (nb_ < 768) ? (bf16_t*)Cout : out2;
            const int cb = (nb_ < 768) ? nb_ : nb_ - 768;
#pragma unroll
            for (int i = 0; i < 4; i++)
#pragma unroll
                for (int j = 0; j < 4; j++)
#pragma unroll
                    for (int r = 0; r < 4; r++) {
                        int row = mb_ + (i << 4) + rowq + r;
                        int col = cb + (j << 4) + colw;
                        float v = fmaxf(acc[i][j][r] + bj[j], 0.f);
                        C[(long)row * Hh + col] = (bf16_t)v;
                    }
        } else {
#pragma unroll
            for (int i = 0; i < 4; i++) {
                const int sAbs = mb_ + (i << 4) + rowq;
                const int b = sAbs >> 10;
                const int sl = sAbs & 1023;
#pragma unroll
                for (int j = 0; j < 4; j++) {
                    const int col = nb_ - 1536 + (j << 4) + colw;
                    bf16x4 o = { (bf16_t)(acc[i][j][0] + bj[j]), (bf16_t)(acc[i][j][1] + bj[j]),
                                 (bf16_t)(acc[i][j][2] + bj[j]), (bf16_t)(acc[i][j][3] + bj[j]) };
                    *(bf16x4*)&out3[((long)b * Hh + col) * Ss + sl] = o;
                }
            }
        }
    } else if constexpr (EPI == EG_SCORE_T) {
        // computed T = k·q^T; rows = keys, cols = queries; store S = T^T (bf16)
        bf16_t* C = (bf16_t*)Cout + (long)bz * sC;
        const int* mk = mask + bz * Ss;
        int mq[4];
#pragma unroll
        for (int j = 0; j < 4; j++) mq[j] = mk[nb_ + (j << 4) + colw];
#pragma unroll
        for (int i = 0; i < 4; i++) {
            const int kbase = mb_ + (i << 4) + rowq;
            int4 mkey = *(const int4*)&mk[kbase];
#pragma unroll
            for (int j = 0; j < 4; j++) {
                const int qrow = nb_ + (j << 4) + colw;
                bf16x4 o;
                o[0] = (mkey.x & mq[j]) ? (bf16_t)(acc[i][j][0] * scale) : (bf16_t)(-1e12f);
                o[1] = (mkey.y & mq[j]) ? (bf16_t)(acc[i][j][1] * scale) : (bf16_t)(-1e12f);
                o[2] = (mkey.z & mq[j]) ? (bf16_t)(acc[i][j][2] * scale) : (bf16_t)(-1e12f);
                o[3] = (mkey.w & mq[j]) ? (bf16_t)(acc[i][j][3] * scale) : (bf16_t)(-1e12f);
                *(bf16x4*)&C[(long)qrow * ldc + kbase] = o;
            }
        }
    } else if constexpr (EPI == EG_FINAL) {
        float* C = (float*)Cout;
        float bj[4];
#pragma unroll
        for (int j = 0; j < 4; j++) bj[j] = bias[nb_ + (j << 4) + colw];
#pragma unroll
        for (int i = 0; i < 4; i++)
#pragma unroll
            for (int j = 0; j < 4; j++)
#pragma unroll
                for (int r = 0; r < 4; r++) {
                    int row = mb_ + (i << 4) + rowq + r;
                    int col = nb_ + (j << 4) + colw;
                    C[(long)row * ldc + col] =
                        acc[i][j][r] + bj[j] + (float)resid[(long)row * ldc + col];
                }
    } else {
        // EG_RELU_BIAS_B16 / EG_B16 -> bf16 output
        bf16_t* C = (bf16_t*)Cout + (long)bz * sC;
        float bj[4] = {0.f, 0.f, 0.f, 0.f};
        if constexpr (EPI == EG_RELU_BIAS_B16) {
#pragma unroll
            for (int j = 0; j < 4; j++) bj[j] = bias[nb_ + (j << 4) + colw];
        }
#pragma unroll
        for (int i = 0; i < 4; i++)
#pragma unroll
            for (int j = 0; j < 4; j++)
#pragma unroll
                for (int r = 0; r < 4; r++) {
                    int row = mb_ + (i << 4) + rowq + r;
                    int col = nb_ + (j << 4) + colw;
                    float v = acc[i][j][r] + bj[j];
                    if constexpr (EPI == EG_RELU_BIAS_B16) v = fmaxf(v, 0.f);
                    C[(long)row * ldc + col] = (bf16_t)v;
                }
    }
}

// ---------------- masked softmax, bf16 in / bf16 out (in place) ----------------
__global__ __launch_bounds__(256) void softmax_rows(bf16_t* __restrict__ S_,
                                                    const int* __restrict__ mask)
{
    const int row = blockIdx.x;
    const int b = row >> 10;
    const int s = row & 1023;
    bf16_t* p = S_ + (long)row * Ss;
    const int* mk = mask + b * Ss;
    const int t = threadIdx.x;
    const int t0 = t << 2;

    bf16x4 v4 = *(const bf16x4*)&p[t0];
    float v0 = (float)v4[0], v1 = (float)v4[1], v2 = (float)v4[2], v3 = (float)v4[3];

    float mx = fmaxf(fmaxf(v0, v1), fmaxf(v2, v3));
#pragma unroll
    for (int off = 32; off; off >>= 1) mx = fmaxf(mx, __shfl_down(mx, off, 64));
    __shared__ float redm[4], reds[4];
    if ((t & 63) == 0) redm[t >> 6] = mx;
    __syncthreads();
    mx = fmaxf(fmaxf(redm[0], redm[1]), fmaxf(redm[2], redm[3]));

    float e0 = __expf(v0 - mx), e1 = __expf(v1 - mx);
    float e2 = __expf(v2 - mx), e3 = __expf(v3 - mx);
    float sm = e0 + e1 + e2 + e3;
#pragma unroll
    for (int off = 32; off; off >>= 1) sm += __shfl_down(sm, off, 64);
    if ((t & 63) == 0) reds[t >> 6] = sm;
    __syncthreads();
    sm = reds[0] + reds[1] + reds[2] + reds[3];

    const float inv = 1.f / sm;
    const float fs = (float)mk[s];
    bf16x4 o = { (bf16_t)(e0 * inv * fs * (float)mk[t0 + 0]),
                 (bf16_t)(e1 * inv * fs * (float)mk[t0 + 1]),
                 (bf16_t)(e2 * inv * fs * (float)mk[t0 + 2]),
                 (bf16_t)(e3 * inv * fs * (float)mk[t0 + 3]) };
    *(bf16x4*)&p[t0] = o;
}

extern "C" void kernel_launch(void* const* d_in, const int* in_sizes, int n_in,
                              void* d_out, int out_size, void* d_ws, size_t ws_size,
                              hipStream_t stream)
{
    const float* x  = (const float*)d_in[0];
    const int* mask = (const int*)d_in[1];
    const float* Wq = (const float*)d_in[2];
    const float* bq = (const float*)d_in[3];
    const float* Wk = (const float*)d_in[4];
    const float* bk = (const float*)d_in[5];
    const float* Wv = (const float*)d_in[6];
    const float* bv = (const float*)d_in[7];
    const float* W1 = (const float*)d_in[8];
    const float* b1 = (const float*)d_in[9];
    const float* W2 = (const float*)d_in[10];
    const float* b2 = (const float*)d_in[11];
    float* out = (float*)d_out;

    // workspace layout (~140 MB)
    char* w = (char*)d_ws;
    bf16_t* xb   = (bf16_t*)(w + 0);            // [16384,768], reused as ctx
    bf16_t* qb   = (bf16_t*)(w + 25165824);     // reused as h1
    bf16_t* kb   = (bf16_t*)(w + 50331648);
    bf16_t* vT   = (bf16_t*)(w + 75497472);     // [16,768,1024]
    bf16_t* sc   = (bf16_t*)(w + 100663296);    // [16,1024,1024] bf16
    bf16_t* wqkv = (bf16_t*)(w + 134217728);    // [2304,768] = Wq|Wk|Wv
    bf16_t* w1b  = (bf16_t*)(w + 137756672);
    bf16_t* w2b  = (bf16_t*)(w + 138936320);
    float*  bqkv = (float*) (w + 140115968);    // [2304]
    bf16_t* ctx  = xb;
    bf16_t* h1   = qb;

    const float inv_sqrt_h = 0.036084391824351615f; // 1/sqrt(768)

    cvt_all<<<15177, 256, 0, stream>>>(x, Wq, Wk, Wv, W1, W2, bq, bk, bv, xb, wqkv, bqkv);

    dim3 blk(256);

    // fused q|k|vT = epi(x · [Wq|Wk|Wv]^T + bqkv)
    mfma_gemm<EG_QKV><<<dim3(18, 128, 1), blk, 0, stream>>>(
        xb, wqkv, bqkv, nullptr, nullptr, qb, kb, vT,
        768, 768, 768, 768, 0, 0, 0, 1.f);

    // sc[q][k] = (k·q^T)^T * scale with mask penalty, bf16
    mfma_gemm<EG_SCORE_T><<<dim3(8, 8, 16), blk, 0, stream>>>(
        kb, qb, nullptr, nullptr, mask, sc, nullptr, nullptr,
        768, 768, 768, 1024, 786432, 786432, 1048576, inv_sqrt_h);

    // masked softmax in place (bf16)
    softmax_rows<<<dim3(MTOK), blk, 0, stream>>>(sc, mask);

    // ctx = sc · vT^T
    mfma_gemm<EG_B16><<<dim3(6, 8, 16), blk, 0, stream>>>(
        sc, vT, nullptr, nullptr, nullptr, ctx, nullptr, nullptr,
        1024, 1024, 1024, 768, 1048576, 786432, 786432, 1.f);

    // h1 = relu(ctx · W1^T + b1)
    mfma_gemm<EG_RELU_BIAS_B16><<<dim3(6, 128, 1), blk, 0, stream>>>(
        ctx, w1b, b1, nullptr, nullptr, h1, nullptr, nullptr,
        768, 768, 768, 768, 0, 0, 0, 1.f);

    // out = h1 · W2^T + b2 + ctx  (fp32)
    mfma_gemm<EG_FINAL><<<dim3(6, 128, 1), blk, 0, stream>>>(
        h1, w2b, b2, ctx, nullptr, out, nullptr, nullptr,
        768, 768, 768, 768, 0, 0, 0, 1.f);
}

// Round 7
// 349.231 us; speedup vs baseline: 1.3680x; 1.1754x over previous
//
#include <hip/hip_runtime.h>
#include <hip/hip_bf16.h>

typedef __bf16 bf16_t;
typedef __bf16 bf16x8 __attribute__((ext_vector_type(8)));
typedef __bf16 bf16x4 __attribute__((ext_vector_type(4)));
typedef float f32x4 __attribute__((ext_vector_type(4)));
typedef unsigned int u32;
typedef const __attribute__((address_space(1))) u32* gptr_t;
typedef __attribute__((address_space(3))) u32* lptr_t;

static constexpr int Bb = 16, Ss = 1024, Hh = 768;

// ---- per-batch mask compaction: tok[b][j] = j-th valid s, cnt[b] = count ----
__global__ __launch_bounds__(256) void compact_mask(
    const int* __restrict__ mask, int* __restrict__ tok, int* __restrict__ cnt)
{
    const int b = blockIdx.x;
    const int t = threadIdx.x;
    const int4 m4 = *(const int4*)&mask[(b << 10) + (t << 2)];
    const int c = (m4.x != 0) + (m4.y != 0) + (m4.z != 0) + (m4.w != 0);
    __shared__ int sb[256];
    sb[t] = c;
    __syncthreads();
    for (int off = 1; off < 256; off <<= 1) {
        int v = (t >= off) ? sb[t - off] : 0;
        __syncthreads();
        sb[t] += v;
        __syncthreads();
    }
    int p = sb[t] - c;  // exclusive prefix
    int* tb = tok + (b << 10);
    if (m4.x) tb[p++] = (t << 2) + 0;
    if (m4.y) tb[p++] = (t << 2) + 1;
    if (m4.z) tb[p++] = (t << 2) + 2;
    if (m4.w) tb[p++] = (t << 2) + 3;
    if (t == 255) cnt[b] = sb[255];
}

// ---- conversions: weights -> bf16 slab, bias pack, x gather-convert to compact xc ----
__global__ __launch_bounds__(256) void cvt_all(
    const float* __restrict__ x,
    const float* __restrict__ w0, const float* __restrict__ w1,
    const float* __restrict__ w2, const float* __restrict__ w3,
    const float* __restrict__ w4,
    const float* __restrict__ bq, const float* __restrict__ bk,
    const float* __restrict__ bv,
    const int* __restrict__ tok, const int* __restrict__ cnt,
    bf16_t* __restrict__ xc, bf16_t* __restrict__ wdst, float* __restrict__ bdst)
{
    const int bx = blockIdx.x;
    const int t = threadIdx.x;
    if (bx < 2880) {
        int seg = bx / 576;
        const float* src = seg == 0 ? w0 : seg == 1 ? w1 : seg == 2 ? w2 : seg == 3 ? w3 : w4;
        int i = (bx % 576) * 256 + t;
        float4 v = ((const float4*)src)[i];
        bf16x4 o = { (bf16_t)v.x, (bf16_t)v.y, (bf16_t)v.z, (bf16_t)v.w };
        ((bf16x4*)(wdst + (long)seg * 589824))[i] = o;
    } else if (bx < 2889) {
        int i = (bx - 2880) * 256 + t;
        if (i < 2304)
            bdst[i] = i < 768 ? bq[i] : i < 1536 ? bk[i - 768] : bv[i - 1536];
    } else {
        const int idx = bx - 2889;
        const int b = idx >> 10, j = idx & 1023;
        if (j < cnt[b] && t < 192) {
            const int s = tok[(b << 10) + j];
            float4 v = ((const float4*)(x + ((long)((b << 10) + s)) * 768))[t];
            bf16x4 o = { (bf16_t)v.x, (bf16_t)v.y, (bf16_t)v.z, (bf16_t)v.w };
            ((bf16x4*)(xc + ((long)((b << 10) + j)) * 768))[t] = o;
        }
    }
}

// ---- cvec = W2 · relu(b1) + b2  (the constant output row for masked tokens) ----
__global__ __launch_bounds__(256) void calc_cvec(
    const float* __restrict__ W2, const float* __restrict__ b1,
    const float* __restrict__ b2, float* __restrict__ cvec)
{
    const int o = blockIdx.x * 256 + threadIdx.x;  // 768 total
    const float* wr = W2 + (long)o * 768;
    float acc = 0.f;
    for (int h = 0; h < 768; h++) acc += wr[h] * fmaxf(b1[h], 0.f);
    cvec[o] = acc + b2[o];
}

// ---- fill masked output rows with cvec ----
__global__ __launch_bounds__(192) void fill_masked(
    const int* __restrict__ mask, const float* __restrict__ cvec, float* __restrict__ out)
{
    const int b = blockIdx.y, s = blockIdx.x;
    if (mask[(b << 10) + s]) return;
    const int t = threadIdx.x;
    float4 v = ((const float4*)cvec)[t];
    ((float4*)(out + ((long)((b << 10) + s)) * 768))[t] = v;
}

// ---------------- async global->LDS 16B ----------------
__device__ __forceinline__ void async_cp16(const void* g, void* l)
{
    __builtin_amdgcn_global_load_lds((gptr_t)g, (lptr_t)l, 16, 0, 0);
}

enum { EG_QKV = 0, EG_SCORE_C = 1, EG_PV = 2, EG_FFN1 = 3, EG_FFN2 = 4 };

// C = epi(A * B^T); 128x128 tile, BK=32, 4 waves 2x2, mfma_f32_16x16x32_bf16 4x4.
// XOR-swizzled LDS (R6: coalesced staging + 0 conflicts). All operands compacted
// per batch; m-tiles (and score n-tiles) early-exit at cnt[bz]; PV K = ceil32(cnt).
// Dupe rows beyond cnt are computed-but-finite; only FFN2's tok-scatter is guarded.
template <int EPI>
__global__ __launch_bounds__(256) void mfma_gemm(
    const bf16_t* __restrict__ A, const bf16_t* __restrict__ B,
    const float* __restrict__ bias, const bf16_t* __restrict__ resid,
    const int* __restrict__ tok, const int* __restrict__ cnt,
    void* __restrict__ Cout, bf16_t* __restrict__ out2, bf16_t* __restrict__ out3,
    int K, int lda, int ldb, long sA, long sB, float scale)
{
    const int bz = blockIdx.z;
    const int cb = cnt[bz];
    const int m0 = blockIdx.y * 128;
    const int n0 = blockIdx.x * 128;
    if (m0 >= cb) return;
    if constexpr (EPI == EG_SCORE_C) { if (n0 >= cb) return; }
    const int Kend = (EPI == EG_PV) ? ((cb + 31) & ~31) : K;

    __shared__ bf16_t Asl[128 * 32];
    __shared__ bf16_t Bsl[128 * 32];

    const int tid = threadIdx.x;
    const int wid = tid >> 6;
    const int lane = tid & 63;
    const int wm = wid & 1, wn = wid >> 1;

    const bf16_t* Ab = A + (long)bz * sA;
    const bf16_t* Bp = B + (long)bz * sB;

    // staging: lane l -> row w*16 + (l>>2), kchunk (l&3)^((l>>3)&3)  (64B-coalesced)
    const int srow = (wid << 4) + (lane >> 2);
    const int scol = ((lane & 3) ^ ((lane >> 3) & 3)) << 3;

    const bf16_t* pa0 = Ab + (long)(m0 + srow) * lda + scol;
    const bf16_t* pa1 = Ab + (long)(m0 + 64 + srow) * lda + scol;
    const bf16_t* pb0 = Bp + (long)(n0 + srow) * ldb + scol;
    const bf16_t* pb1 = Bp + (long)(n0 + 64 + srow) * ldb + scol;

    bf16_t* la = &Asl[wid << 9];
    bf16_t* lb = &Bsl[wid << 9];

    // fragment read: row=lane&15, kchunk=(lane>>4)^((lane>>1)&3)  (2-way = free)
    const int frag_off = ((lane & 15) << 5) + (((lane >> 4) ^ ((lane >> 1) & 3)) << 3);

    f32x4 acc[4][4] = {};

    for (int k0 = 0; k0 < Kend; k0 += 32) {
        async_cp16(pa0 + k0, la);
        async_cp16(pa1 + k0, la + 2048);
        async_cp16(pb0 + k0, lb);
        async_cp16(pb1 + k0, lb + 2048);
        __syncthreads();

        bf16x8 af[4], bfr[4];
#pragma unroll
        for (int i = 0; i < 4; i++)
            af[i] = *(const bf16x8*)&Asl[(((wm << 2) + i) << 9) + frag_off];
#pragma unroll
        for (int j = 0; j < 4; j++)
            bfr[j] = *(const bf16x8*)&Bsl[(((wn << 2) + j) << 9) + frag_off];
#pragma unroll
        for (int i = 0; i < 4; i++)
#pragma unroll
            for (int j = 0; j < 4; j++)
                acc[i][j] = __builtin_amdgcn_mfma_f32_16x16x32_bf16(af[i], bfr[j], acc[i][j], 0, 0, 0);
        __syncthreads();
    }

    // epilogue — C/D per 16x16 tile: col = lane&15, row = (lane>>4)*4 + reg
    const int mb_ = m0 + (wm << 6);
    const int nb_ = n0 + (wn << 6);
    const int colw = lane & 15;
    const int rowq = (lane >> 4) << 2;

    if constexpr (EPI == EG_QKV) {
        float bj[4];
#pragma unroll
        for (int j = 0; j < 4; j++) bj[j] = bias[nb_ + (j << 4) + colw];
        if (nb_ < 1536) {
            bf16_t* C = ((nb_ < 768) ? (bf16_t*)Cout : out2) + (long)bz * 786432;
            const int cbase = (nb_ < 768) ? nb_ : nb_ - 768;
#pragma unroll
            for (int i = 0; i < 4; i++)
#pragma unroll
                for (int j = 0; j < 4; j++)
#pragma unroll
                    for (int r = 0; r < 4; r++) {
                        int row = mb_ + (i << 4) + rowq + r;
                        int col = cbase + (j << 4) + colw;
                        C[(long)row * Hh + col] = (bf16_t)fmaxf(acc[i][j][r] + bj[j], 0.f);
                    }
        } else {
            bf16_t* C = out3 + (long)bz * 786432;  // vTc[b][h][jc]
#pragma unroll
            for (int i = 0; i < 4; i++) {
                const int jc0 = mb_ + (i << 4) + rowq;
#pragma unroll
                for (int j = 0; j < 4; j++) {
                    const int col = nb_ - 1536 + (j << 4) + colw;
                    bf16x4 o = { (bf16_t)(acc[i][j][0] + bj[j]), (bf16_t)(acc[i][j][1] + bj[j]),
                                 (bf16_t)(acc[i][j][2] + bj[j]), (bf16_t)(acc[i][j][3] + bj[j]) };
                    *(bf16x4*)&C[(long)col * 1024 + jc0] = o;
                }
            }
        }
    } else if constexpr (EPI == EG_SCORE_C) {
        // computed T = k·q^T (rows=keys); store S = T^T, no mask (all tokens valid)
        bf16_t* C = (bf16_t*)Cout + (long)bz * 1048576;
#pragma unroll
        for (int i = 0; i < 4; i++) {
            const int kbase = mb_ + (i << 4) + rowq;
#pragma unroll
            for (int j = 0; j < 4; j++) {
                const int qrow = nb_ + (j << 4) + colw;
                bf16x4 o = { (bf16_t)(acc[i][j][0] * scale), (bf16_t)(acc[i][j][1] * scale),
                             (bf16_t)(acc[i][j][2] * scale), (bf16_t)(acc[i][j][3] * scale) };
                *(bf16x4*)&C[(long)qrow * 1024 + kbase] = o;
            }
        }
    } else if constexpr (EPI == EG_FFN2) {
        float* outp = (float*)Cout;
        const bf16_t* crow = resid + (long)bz * 786432;
        const int* tb = tok + (bz << 10);
        float bj[4];
#pragma unroll
        for (int j = 0; j < 4; j++) bj[j] = bias[nb_ + (j << 4) + colw];
#pragma unroll
        for (int i = 0; i < 4; i++)
#pragma unroll
            for (int r = 0; r < 4; r++) {
                const int jq = mb_ + (i << 4) + rowq + r;
                if (jq < cb) {
                    const int s = tb[jq];
                    float* orow = outp + ((long)((bz << 10) + s)) * 768;
                    const bf16_t* cr = crow + (long)jq * 768;
#pragma unroll
                    for (int j = 0; j < 4; j++) {
                        const int col = nb_ + (j << 4) + colw;
                        orow[col] = acc[i][j][r] + bj[j] + (float)cr[col];
                    }
                }
            }
    } else {
        // EG_PV (plain bf16) / EG_FFN1 (relu+bias bf16), compact per-batch
        bf16_t* C = (bf16_t*)Cout + (long)bz * 786432;
        float bj[4] = {0.f, 0.f, 0.f, 0.f};
        if constexpr (EPI == EG_FFN1) {
#pragma unroll
            for (int j = 0; j < 4; j++) bj[j] = bias[nb_ + (j << 4) + colw];
        }
#pragma unroll
        for (int i = 0; i < 4; i++)
#pragma unroll
            for (int j = 0; j < 4; j++)
#pragma unroll
                for (int r = 0; r < 4; r++) {
                    int row = mb_ + (i << 4) + rowq + r;
                    int col = nb_ + (j << 4) + colw;
                    float v = acc[i][j][r] + bj[j];
                    if constexpr (EPI == EG_FFN1) v = fmaxf(v, 0.f);
                    C[(long)row * Hh + col] = (bf16_t)v;
                }
    }
}

// ---- softmax over compact keys: validity is just col < cnt (no mask loads) ----
__global__ __launch_bounds__(256) void softmax_rows(bf16_t* __restrict__ S_,
                                                    const int* __restrict__ cnt)
{
    const int b = blockIdx.y, jq = blockIdx.x;
    const int cb = cnt[b];
    if (jq >= cb) return;
    bf16_t* p = S_ + (((long)(b << 10)) + jq) * 1024;
    const int t = threadIdx.x;
    const int t0 = t << 2;

    bf16x4 v4 = *(const bf16x4*)&p[t0];
    float v0 = (t0 + 0 < cb) ? (float)v4[0] : -1e30f;
    float v1 = (t0 + 1 < cb) ? (float)v4[1] : -1e30f;
    float v2 = (t0 + 2 < cb) ? (float)v4[2] : -1e30f;
    float v3 = (t0 + 3 < cb) ? (float)v4[3] : -1e30f;

    float mx = fmaxf(fmaxf(v0, v1), fmaxf(v2, v3));
#pragma unroll
    for (int off = 32; off; off >>= 1) mx = fmaxf(mx, __shfl_down(mx, off, 64));
    __shared__ float redm[4], reds[4];
    if ((t & 63) == 0) redm[t >> 6] = mx;
    __syncthreads();
    mx = fmaxf(fmaxf(redm[0], redm[1]), fmaxf(redm[2], redm[3]));

    // invalid lanes: exp(-1e30 - mx) underflows to exactly 0
    float e0 = __expf(v0 - mx), e1 = __expf(v1 - mx);
    float e2 = __expf(v2 - mx), e3 = __expf(v3 - mx);
    float sm = e0 + e1 + e2 + e3;
#pragma unroll
    for (int off = 32; off; off >>= 1) sm += __shfl_down(sm, off, 64);
    if ((t & 63) == 0) reds[t >> 6] = sm;
    __syncthreads();
    sm = reds[0] + reds[1] + reds[2] + reds[3];

    const float inv = 1.f / sm;
    bf16x4 o = { (bf16_t)(e0 * inv), (bf16_t)(e1 * inv),
                 (bf16_t)(e2 * inv), (bf16_t)(e3 * inv) };
    *(bf16x4*)&p[t0] = o;
}

extern "C" void kernel_launch(void* const* d_in, const int* in_sizes, int n_in,
                              void* d_out, int out_size, void* d_ws, size_t ws_size,
                              hipStream_t stream)
{
    const float* x  = (const float*)d_in[0];
    const int* mask = (const int*)d_in[1];
    const float* Wq = (const float*)d_in[2];
    const float* bq = (const float*)d_in[3];
    const float* Wk = (const float*)d_in[4];
    const float* bk = (const float*)d_in[5];
    const float* Wv = (const float*)d_in[6];
    const float* bv = (const float*)d_in[7];
    const float* W1 = (const float*)d_in[8];
    const float* b1 = (const float*)d_in[9];
    const float* W2 = (const float*)d_in[10];
    const float* b2 = (const float*)d_in[11];
    float* out = (float*)d_out;

    // workspace layout (~140.2 MB)
    char* w = (char*)d_ws;
    bf16_t* xc   = (bf16_t*)(w + 0);            // [16][1024][768] compact, reused as ctxc
    bf16_t* qc   = (bf16_t*)(w + 25165824);     // reused as h1c
    bf16_t* kc   = (bf16_t*)(w + 50331648);
    bf16_t* vTc  = (bf16_t*)(w + 75497472);     // [16][768][1024] compact cols
    bf16_t* sc   = (bf16_t*)(w + 100663296);    // [16][1024][1024] bf16
    bf16_t* wqkv = (bf16_t*)(w + 134217728);    // [2304,768] = Wq|Wk|Wv
    bf16_t* w1b  = (bf16_t*)(w + 137756672);
    bf16_t* w2b  = (bf16_t*)(w + 138936320);
    float*  bqkv = (float*) (w + 140115968);    // [2304]
    int*    tok  = (int*)   (w + 140125184);    // [16][1024]
    int*    cnt  = (int*)   (w + 140190720);    // [16]
    float*  cvec = (float*) (w + 140190784);    // [768]
    bf16_t* ctxc = xc;
    bf16_t* h1c  = qc;

    const float inv_sqrt_h = 0.036084391824351615f; // 1/sqrt(768)
    dim3 blk(256);

    compact_mask<<<16, blk, 0, stream>>>(mask, tok, cnt);
    cvt_all<<<19273, blk, 0, stream>>>(x, Wq, Wk, Wv, W1, W2, bq, bk, bv,
                                       tok, cnt, xc, wqkv, bqkv);
    calc_cvec<<<3, blk, 0, stream>>>(W2, b1, b2, cvec);

    // qc|kc|vTc = epi(xc · [Wq|Wk|Wv]^T + bqkv), compact rows
    mfma_gemm<EG_QKV><<<dim3(18, 8, 16), blk, 0, stream>>>(
        xc, wqkv, bqkv, nullptr, tok, cnt, qc, kc, vTc,
        768, 768, 768, 786432, 0, 1.f);

    // sc[jq][jk] = (kc·qc^T)^T * scale  (both dims compact)
    mfma_gemm<EG_SCORE_C><<<dim3(8, 8, 16), blk, 0, stream>>>(
        kc, qc, nullptr, nullptr, tok, cnt, sc, nullptr, nullptr,
        768, 768, 768, 786432, 786432, inv_sqrt_h);

    // softmax over valid keys, in place
    softmax_rows<<<dim3(1024, 16), blk, 0, stream>>>(sc, cnt);

    // ctxc = sc · vTc^T   (K = ceil32(cnt) per batch)
    mfma_gemm<EG_PV><<<dim3(6, 8, 16), blk, 0, stream>>>(
        sc, vTc, nullptr, nullptr, tok, cnt, ctxc, nullptr, nullptr,
        0, 1024, 1024, 1048576, 786432, 1.f);

    // h1c = relu(ctxc · W1^T + b1)
    mfma_gemm<EG_FFN1><<<dim3(6, 8, 16), blk, 0, stream>>>(
        ctxc, w1b, b1, nullptr, tok, cnt, h1c, nullptr, nullptr,
        768, 768, 768, 786432, 0, 1.f);

    // out[b][tok[jq]] = h1c · W2^T + b2 + ctxc   (scatter, fp32)
    mfma_gemm<EG_FFN2><<<dim3(6, 8, 16), blk, 0, stream>>>(
        h1c, w2b, b2, ctxc, tok, cnt, out, nullptr, nullptr,
        768, 768, 768, 786432, 0, 1.f);

    // masked rows: out = cvec
    fill_masked<<<dim3(1024, 16), dim3(192), 0, stream>>>(mask, cvec, out);
}

// Round 8
// 329.014 us; speedup vs baseline: 1.4521x; 1.0614x over previous
//
#include <hip/hip_runtime.h>
#include <hip/hip_bf16.h>

typedef __bf16 bf16_t;
typedef __bf16 bf16x8 __attribute__((ext_vector_type(8)));
typedef __bf16 bf16x4 __attribute__((ext_vector_type(4)));
typedef float f32x4 __attribute__((ext_vector_type(4)));
typedef unsigned int u32;
typedef const __attribute__((address_space(1))) u32* gptr_t;
typedef __attribute__((address_space(3))) u32* lptr_t;

static constexpr int Bb = 16, Ss = 1024, Hh = 768;

// ---- per-batch mask compaction: tok[b][j] = j-th valid s, cnt[b] = count ----
__global__ __launch_bounds__(256) void compact_mask(
    const int* __restrict__ mask, int* __restrict__ tok, int* __restrict__ cnt)
{
    const int b = blockIdx.x;
    const int t = threadIdx.x;
    const int4 m4 = *(const int4*)&mask[(b << 10) + (t << 2)];
    const int c = (m4.x != 0) + (m4.y != 0) + (m4.z != 0) + (m4.w != 0);
    __shared__ int sb[256];
    sb[t] = c;
    __syncthreads();
    for (int off = 1; off < 256; off <<= 1) {
        int v = (t >= off) ? sb[t - off] : 0;
        __syncthreads();
        sb[t] += v;
        __syncthreads();
    }
    int p = sb[t] - c;  // exclusive prefix
    int* tb = tok + (b << 10);
    if (m4.x) tb[p++] = (t << 2) + 0;
    if (m4.y) tb[p++] = (t << 2) + 1;
    if (m4.z) tb[p++] = (t << 2) + 2;
    if (m4.w) tb[p++] = (t << 2) + 3;
    if (t == 255) cnt[b] = sb[255];
}

// ---- conversions + cvec: weights -> bf16 slab, bias pack, x gather-convert,
// ---- and cvec = W2·relu(b1)+b2 (coalesced block-parallel reduction) ----
__global__ __launch_bounds__(256) void cvt_all(
    const float* __restrict__ x,
    const float* __restrict__ w0, const float* __restrict__ w1,
    const float* __restrict__ w2, const float* __restrict__ w3,
    const float* __restrict__ w4,
    const float* __restrict__ bq, const float* __restrict__ bk,
    const float* __restrict__ bv,
    const float* __restrict__ b1, const float* __restrict__ b2,
    const int* __restrict__ tok, const int* __restrict__ cnt,
    bf16_t* __restrict__ xc, bf16_t* __restrict__ wdst, float* __restrict__ bdst,
    float* __restrict__ cvec)
{
    const int bx = blockIdx.x;
    const int t = threadIdx.x;
    if (bx < 2880) {
        int seg = bx / 576;
        const float* src = seg == 0 ? w0 : seg == 1 ? w1 : seg == 2 ? w2 : seg == 3 ? w3 : w4;
        int i = (bx % 576) * 256 + t;
        float4 v = ((const float4*)src)[i];
        bf16x4 o = { (bf16_t)v.x, (bf16_t)v.y, (bf16_t)v.z, (bf16_t)v.w };
        ((bf16x4*)(wdst + (long)seg * 589824))[i] = o;
    } else if (bx < 2889) {
        int i = (bx - 2880) * 256 + t;
        if (i < 2304)
            bdst[i] = i < 768 ? bq[i] : i < 1536 ? bk[i - 768] : bv[i - 1536];
    } else if (bx < 19273) {
        const int idx = bx - 2889;
        const int b = idx >> 10, j = idx & 1023;
        if (j < cnt[b] && t < 192) {
            const int s = tok[(b << 10) + j];
            float4 v = ((const float4*)(x + ((long)((b << 10) + s)) * 768))[t];
            bf16x4 o = { (bf16_t)v.x, (bf16_t)v.y, (bf16_t)v.z, (bf16_t)v.w };
            ((bf16x4*)(xc + ((long)((b << 10) + j)) * 768))[t] = o;
        }
    } else {
        // cvec: 96 blocks x 8 outputs; 32 lanes reduce one W2 row (coalesced)
        const int o = ((bx - 19273) << 3) + (t >> 5);
        const int l = t & 31;
        const float* wr = w4 + (long)o * 768;
        float acc = 0.f;
        for (int h = l; h < 768; h += 32) acc += wr[h] * fmaxf(b1[h], 0.f);
#pragma unroll
        for (int off = 16; off; off >>= 1) acc += __shfl_down(acc, off, 32);
        if (l == 0) cvec[o] = acc + b2[o];
    }
}

// ---------------- async global->LDS 16B ----------------
__device__ __forceinline__ void async_cp16(const void* g, void* l)
{
    __builtin_amdgcn_global_load_lds((gptr_t)g, (lptr_t)l, 16, 0, 0);
}

enum { EG_QKV = 0, EG_SCORE_C = 1, EG_PV = 2, EG_FFN1 = 3, EG_FFN2 = 4 };

// C = epi(A * B^T); 128x128 tile, BK=32, 4 waves 2x2, mfma_f32_16x16x32_bf16 4x4.
// XOR-swizzled LDS (R6: coalesced staging + 0 conflicts). All operands compacted
// per batch; m-tiles (and score n-tiles) early-exit at cnt[bz]; PV K = ceil32(cnt).
// Dupe rows beyond cnt are computed-but-finite; only FFN2's tok-scatter is guarded.
template <int EPI>
__global__ __launch_bounds__(256) void mfma_gemm(
    const bf16_t* __restrict__ A, const bf16_t* __restrict__ B,
    const float* __restrict__ bias, const bf16_t* __restrict__ resid,
    const int* __restrict__ tok, const int* __restrict__ cnt,
    void* __restrict__ Cout, bf16_t* __restrict__ out2, bf16_t* __restrict__ out3,
    int K, int lda, int ldb, long sA, long sB, float scale)
{
    const int bz = blockIdx.z;
    const int cb = cnt[bz];
    const int m0 = blockIdx.y * 128;
    const int n0 = blockIdx.x * 128;
    if (m0 >= cb) return;
    if constexpr (EPI == EG_SCORE_C) { if (n0 >= cb) return; }
    const int Kend = (EPI == EG_PV) ? ((cb + 31) & ~31) : K;

    __shared__ bf16_t Asl[128 * 32];
    __shared__ bf16_t Bsl[128 * 32];

    const int tid = threadIdx.x;
    const int wid = tid >> 6;
    const int lane = tid & 63;
    const int wm = wid & 1, wn = wid >> 1;

    const bf16_t* Ab = A + (long)bz * sA;
    const bf16_t* Bp = B + (long)bz * sB;

    // staging: lane l -> row w*16 + (l>>2), kchunk (l&3)^((l>>3)&3)  (64B-coalesced)
    const int srow = (wid << 4) + (lane >> 2);
    const int scol = ((lane & 3) ^ ((lane >> 3) & 3)) << 3;

    const bf16_t* pa0 = Ab + (long)(m0 + srow) * lda + scol;
    const bf16_t* pa1 = Ab + (long)(m0 + 64 + srow) * lda + scol;
    const bf16_t* pb0 = Bp + (long)(n0 + srow) * ldb + scol;
    const bf16_t* pb1 = Bp + (long)(n0 + 64 + srow) * ldb + scol;

    bf16_t* la = &Asl[wid << 9];
    bf16_t* lb = &Bsl[wid << 9];

    // fragment read: row=lane&15, kchunk=(lane>>4)^((lane>>1)&3)  (2-way = free)
    const int frag_off = ((lane & 15) << 5) + (((lane >> 4) ^ ((lane >> 1) & 3)) << 3);

    f32x4 acc[4][4] = {};

    for (int k0 = 0; k0 < Kend; k0 += 32) {
        async_cp16(pa0 + k0, la);
        async_cp16(pa1 + k0, la + 2048);
        async_cp16(pb0 + k0, lb);
        async_cp16(pb1 + k0, lb + 2048);
        __syncthreads();

        bf16x8 af[4], bfr[4];
#pragma unroll
        for (int i = 0; i < 4; i++)
            af[i] = *(const bf16x8*)&Asl[(((wm << 2) + i) << 9) + frag_off];
#pragma unroll
        for (int j = 0; j < 4; j++)
            bfr[j] = *(const bf16x8*)&Bsl[(((wn << 2) + j) << 9) + frag_off];
#pragma unroll
        for (int i = 0; i < 4; i++)
#pragma unroll
            for (int j = 0; j < 4; j++)
                acc[i][j] = __builtin_amdgcn_mfma_f32_16x16x32_bf16(af[i], bfr[j], acc[i][j], 0, 0, 0);
        __syncthreads();
    }

    // epilogue — C/D per 16x16 tile: col = lane&15, row = (lane>>4)*4 + reg
    const int mb_ = m0 + (wm << 6);
    const int nb_ = n0 + (wn << 6);
    const int colw = lane & 15;
    const int rowq = (lane >> 4) << 2;

    if constexpr (EPI == EG_QKV) {
        float bj[4];
#pragma unroll
        for (int j = 0; j < 4; j++) bj[j] = bias[nb_ + (j << 4) + colw];
        if (nb_ < 1536) {
            bf16_t* C = ((nb_ < 768) ? (bf16_t*)Cout : out2) + (long)bz * 786432;
            const int cbase = (nb_ < 768) ? nb_ : nb_ - 768;
#pragma unroll
            for (int i = 0; i < 4; i++)
#pragma unroll
                for (int j = 0; j < 4; j++)
#pragma unroll
                    for (int r = 0; r < 4; r++) {
                        int row = mb_ + (i << 4) + rowq + r;
                        int col = cbase + (j << 4) + colw;
                        C[(long)row * Hh + col] = (bf16_t)fmaxf(acc[i][j][r] + bj[j], 0.f);
                    }
        } else {
            bf16_t* C = out3 + (long)bz * 786432;  // vTc[b][h][jc]
#pragma unroll
            for (int i = 0; i < 4; i++) {
                const int jc0 = mb_ + (i << 4) + rowq;
#pragma unroll
                for (int j = 0; j < 4; j++) {
                    const int col = nb_ - 1536 + (j << 4) + colw;
                    bf16x4 o = { (bf16_t)(acc[i][j][0] + bj[j]), (bf16_t)(acc[i][j][1] + bj[j]),
                                 (bf16_t)(acc[i][j][2] + bj[j]), (bf16_t)(acc[i][j][3] + bj[j]) };
                    *(bf16x4*)&C[(long)col * 1024 + jc0] = o;
                }
            }
        }
    } else if constexpr (EPI == EG_SCORE_C) {
        // computed T = k·q^T (rows=keys); store S = T^T, no mask (all tokens valid)
        bf16_t* C = (bf16_t*)Cout + (long)bz * 1048576;
#pragma unroll
        for (int i = 0; i < 4; i++) {
            const int kbase = mb_ + (i << 4) + rowq;
#pragma unroll
            for (int j = 0; j < 4; j++) {
                const int qrow = nb_ + (j << 4) + colw;
                bf16x4 o = { (bf16_t)(acc[i][j][0] * scale), (bf16_t)(acc[i][j][1] * scale),
                             (bf16_t)(acc[i][j][2] * scale), (bf16_t)(acc[i][j][3] * scale) };
                *(bf16x4*)&C[(long)qrow * 1024 + kbase] = o;
            }
        }
    } else if constexpr (EPI == EG_FFN2) {
        float* outp = (float*)Cout;
        const bf16_t* crow = resid + (long)bz * 786432;
        const int* tb = tok + (bz << 10);
        float bj[4];
#pragma unroll
        for (int j = 0; j < 4; j++) bj[j] = bias[nb_ + (j << 4) + colw];
#pragma unroll
        for (int i = 0; i < 4; i++)
#pragma unroll
            for (int r = 0; r < 4; r++) {
                const int jq = mb_ + (i << 4) + rowq + r;
                if (jq < cb) {
                    const int s = tb[jq];
                    float* orow = outp + ((long)((bz << 10) + s)) * 768;
                    const bf16_t* cr = crow + (long)jq * 768;
#pragma unroll
                    for (int j = 0; j < 4; j++) {
                        const int col = nb_ + (j << 4) + colw;
                        orow[col] = acc[i][j][r] + bj[j] + (float)cr[col];
                    }
                }
            }
    } else {
        // EG_PV (plain bf16) / EG_FFN1 (relu+bias bf16), compact per-batch
        bf16_t* C = (bf16_t*)Cout + (long)bz * 786432;
        float bj[4] = {0.f, 0.f, 0.f, 0.f};
        if constexpr (EPI == EG_FFN1) {
#pragma unroll
            for (int j = 0; j < 4; j++) bj[j] = bias[nb_ + (j << 4) + colw];
        }
#pragma unroll
        for (int i = 0; i < 4; i++)
#pragma unroll
            for (int j = 0; j < 4; j++)
#pragma unroll
                for (int r = 0; r < 4; r++) {
                    int row = mb_ + (i << 4) + rowq + r;
                    int col = nb_ + (j << 4) + colw;
                    float v = acc[i][j][r] + bj[j];
                    if constexpr (EPI == EG_FFN1) v = fmaxf(v, 0.f);
                    C[(long)row * Hh + col] = (bf16_t)v;
                }
    }
}

// ---- z=0: softmax over compact keys (validity = col < cnt, no mask loads)
// ---- z=1: fill masked output rows with cvec (disjoint from FFN2's rows)
__global__ __launch_bounds__(256) void softmax_rows(
    bf16_t* __restrict__ S_, const int* __restrict__ cnt,
    const int* __restrict__ mask, const float* __restrict__ cvec,
    float* __restrict__ out)
{
    const int b = blockIdx.y;
    const int t = threadIdx.x;

    if (blockIdx.z == 1) {
        const int s = blockIdx.x;
        if (t >= 192 || mask[(b << 10) + s]) return;
        float4 v = ((const float4*)cvec)[t];
        ((float4*)(out + ((long)((b << 10) + s)) * 768))[t] = v;
        return;
    }

    const int jq = blockIdx.x;
    const int cb = cnt[b];
    if (jq >= cb) return;
    bf16_t* p = S_ + (((long)(b << 10)) + jq) * 1024;
    const int t0 = t << 2;

    bf16x4 v4 = *(const bf16x4*)&p[t0];
    float v0 = (t0 + 0 < cb) ? (float)v4[0] : -1e30f;
    float v1 = (t0 + 1 < cb) ? (float)v4[1] : -1e30f;
    float v2 = (t0 + 2 < cb) ? (float)v4[2] : -1e30f;
    float v3 = (t0 + 3 < cb) ? (float)v4[3] : -1e30f;

    float mx = fmaxf(fmaxf(v0, v1), fmaxf(v2, v3));
#pragma unroll
    for (int off = 32; off; off >>= 1) mx = fmaxf(mx, __shfl_down(mx, off, 64));
    __shared__ float redm[4], reds[4];
    if ((t & 63) == 0) redm[t >> 6] = mx;
    __syncthreads();
    mx = fmaxf(fmaxf(redm[0], redm[1]), fmaxf(redm[2], redm[3]));

    // invalid lanes: exp(-1e30 - mx) underflows to exactly 0
    float e0 = __expf(v0 - mx), e1 = __expf(v1 - mx);
    float e2 = __expf(v2 - mx), e3 = __expf(v3 - mx);
    float sm = e0 + e1 + e2 + e3;
#pragma unroll
    for (int off = 32; off; off >>= 1) sm += __shfl_down(sm, off, 64);
    if ((t & 63) == 0) reds[t >> 6] = sm;
    __syncthreads();
    sm = reds[0] + reds[1] + reds[2] + reds[3];

    const float inv = 1.f / sm;
    bf16x4 o = { (bf16_t)(e0 * inv), (bf16_t)(e1 * inv),
                 (bf16_t)(e2 * inv), (bf16_t)(e3 * inv) };
    *(bf16x4*)&p[t0] = o;
}

extern "C" void kernel_launch(void* const* d_in, const int* in_sizes, int n_in,
                              void* d_out, int out_size, void* d_ws, size_t ws_size,
                              hipStream_t stream)
{
    const float* x  = (const float*)d_in[0];
    const int* mask = (const int*)d_in[1];
    const float* Wq = (const float*)d_in[2];
    const float* bq = (const float*)d_in[3];
    const float* Wk = (const float*)d_in[4];
    const float* bk = (const float*)d_in[5];
    const float* Wv = (const float*)d_in[6];
    const float* bv = (const float*)d_in[7];
    const float* W1 = (const float*)d_in[8];
    const float* b1 = (const float*)d_in[9];
    const float* W2 = (const float*)d_in[10];
    const float* b2 = (const float*)d_in[11];
    float* out = (float*)d_out;

    // workspace layout (~140.2 MB)
    char* w = (char*)d_ws;
    bf16_t* xc   = (bf16_t*)(w + 0);            // [16][1024][768] compact, reused as ctxc
    bf16_t* qc   = (bf16_t*)(w + 25165824);     // reused as h1c
    bf16_t* kc   = (bf16_t*)(w + 50331648);
    bf16_t* vTc  = (bf16_t*)(w + 75497472);     // [16][768][1024] compact cols
    bf16_t* sc   = (bf16_t*)(w + 100663296);    // [16][1024][1024] bf16
    bf16_t* wqkv = (bf16_t*)(w + 134217728);    // [2304,768] = Wq|Wk|Wv
    bf16_t* w1b  = (bf16_t*)(w + 137756672);
    bf16_t* w2b  = (bf16_t*)(w + 138936320);
    float*  bqkv = (float*) (w + 140115968);    // [2304]
    int*    tok  = (int*)   (w + 140125184);    // [16][1024]
    int*    cnt  = (int*)   (w + 140190720);    // [16]
    float*  cvec = (float*) (w + 140190784);    // [768]
    bf16_t* ctxc = xc;
    bf16_t* h1c  = qc;

    const float inv_sqrt_h = 0.036084391824351615f; // 1/sqrt(768)
    dim3 blk(256);

    compact_mask<<<16, blk, 0, stream>>>(mask, tok, cnt);
    cvt_all<<<19369, blk, 0, stream>>>(x, Wq, Wk, Wv, W1, W2, bq, bk, bv, b1, b2,
                                       tok, cnt, xc, wqkv, bqkv, cvec);

    // qc|kc|vTc = epi(xc · [Wq|Wk|Wv]^T + bqkv), compact rows
    mfma_gemm<EG_QKV><<<dim3(18, 8, 16), blk, 0, stream>>>(
        xc, wqkv, bqkv, nullptr, tok, cnt, qc, kc, vTc,
        768, 768, 768, 786432, 0, 1.f);

    // sc[jq][jk] = (kc·qc^T)^T * scale  (both dims compact)
    mfma_gemm<EG_SCORE_C><<<dim3(8, 8, 16), blk, 0, stream>>>(
        kc, qc, nullptr, nullptr, tok, cnt, sc, nullptr, nullptr,
        768, 768, 768, 786432, 786432, inv_sqrt_h);

    // z=0: softmax over valid keys in place; z=1: masked out rows = cvec
    softmax_rows<<<dim3(1024, 16, 2), blk, 0, stream>>>(sc, cnt, mask, cvec, out);

    // ctxc = sc · vTc^T   (K = ceil32(cnt) per batch)
    mfma_gemm<EG_PV><<<dim3(6, 8, 16), blk, 0, stream>>>(
        sc, vTc, nullptr, nullptr, tok, cnt, ctxc, nullptr, nullptr,
        0, 1024, 1024, 1048576, 786432, 1.f);

    // h1c = relu(ctxc · W1^T + b1)
    mfma_gemm<EG_FFN1><<<dim3(6, 8, 16), blk, 0, stream>>>(
        ctxc, w1b, b1, nullptr, tok, cnt, h1c, nullptr, nullptr,
        768, 768, 768, 786432, 0, 1.f);

    // out[b][tok[jq]] = h1c · W2^T + b2 + ctxc   (scatter, fp32)
    mfma_gemm<EG_FFN2><<<dim3(6, 8, 16), blk, 0, stream>>>(
        h1c, w2b, b2, ctxc, tok, cnt, out, nullptr, nullptr,
        768, 768, 768, 786432, 0, 1.f);
}